// Round 22
// baseline (188.840 us; speedup 1.0000x reference)
//
#include <hip/hip_runtime.h>
#include <hip/hip_bf16.h>

#define BATCH 64
#define MDIM 512
#define NDIM 1024
#define KDIM 1024

#define BM 256
#define BN 256
#define BK 64
#define NKT (KDIM / BK)     // 16 K-tiles

typedef __attribute__((ext_vector_type(4))) float f32x4;
typedef __attribute__((ext_vector_type(8))) short bf16x8;
typedef __attribute__((ext_vector_type(4))) unsigned int u32x4;

__device__ __forceinline__ unsigned int cvt2(float lo, float hi) {
    __hip_bfloat162 h = __float22bfloat162_rn(float2{lo, hi});
    return *(unsigned int*)&h;
}

#define MFMA16(a, b, c) __builtin_amdgcn_mfma_f32_16x16x32_bf16((a), (b), (c), 0, 0, 0)
#define SB0 __builtin_amdgcn_sched_barrier(0)
#define WAITLG(n) do { asm volatile("s_waitcnt lgkmcnt(" #n ")" ::: "memory"); SB0; } while (0)
#define BAR do { SB0; __builtin_amdgcn_s_barrier(); SB0; } while (0)

// 1024 threads / 16 waves of 64x64 wave-tiles; launch_bounds(1024,4)
// requests 4 waves/SIMD (unified reg cap 128, m69 occupancy step).
__global__ __launch_bounds__(1024, 4)
void grouped_fc_kernel(const float* __restrict__ X,
                       const float* __restrict__ W,
                       const float* __restrict__ Bias,
                       float* __restrict__ Out) {
    // XCD swizzle (bijective: 512 % 8 == 0)
    const int swz  = (blockIdx.x & 7) * 64 + (blockIdx.x >> 3);
    const int bidx = swz >> 3;
    const int tile = swz & 7;
    const int tm = tile & 1;
    const int tn = tile >> 1;

    const int tid  = threadIdx.x;
    const int lane = tid & 63;
    const int wid  = tid >> 6;     // 0..15
    const int wm   = wid & 3;      // 4 wave rows (64 out-rows each)
    const int wn   = wid >> 2;     // 4 wave cols (64 out-cols each)

    // [row][64] bf16 = 8 x 16B slots/row; slot s at s ^ (row&7).
    // R9/R13/R21-measured: SQ_LDS_BANK_CONFLICT == 0. 128 KB.
    __shared__ unsigned short ldsA[2][BM][BK];
    __shared__ unsigned short ldsB[2][BN][BK];

    const float* srcA = X + ((size_t)bidx * MDIM + (size_t)tm * BM) * KDIM;
    const float* srcB = W + ((size_t)bidx * NDIM + (size_t)tn * BN) * KDIM;

    // staging: 4 threads/row over 256 rows (1024 threads), 16 fp32 each ->
    // one ISSUE covers a full 256x64 operand tile.
    const int s_r  = tid >> 2;
    const int s_cf = (tid & 3) * 16;
    const int s_x  = s_r & 7;
    const int so0  = (((tid & 3) * 2)     ^ s_x) * 8;
    const int so1  = (((tid & 3) * 2 + 1) ^ s_x) * 8;

    f32x4 stA[4], stB[4];          // 2 x 16 VGPR staging sets

    auto ISSUE = [&](const float* srcbase, int kt_, f32x4 (&s)[4]) {
        const float* p = srcbase + (size_t)s_r * KDIM + kt_ * BK + s_cf;
#pragma unroll
        for (int v = 0; v < 4; ++v) s[v] = *(const f32x4*)(p + v * 4);
    };

    auto CVTW = [&](unsigned short* ldsbase, f32x4 (&s)[4]) {
        u32x4 w0, w1;
        w0[0] = cvt2(s[0][0], s[0][1]); w0[1] = cvt2(s[0][2], s[0][3]);
        w0[2] = cvt2(s[1][0], s[1][1]); w0[3] = cvt2(s[1][2], s[1][3]);
        w1[0] = cvt2(s[2][0], s[2][1]); w1[1] = cvt2(s[2][2], s[2][3]);
        w1[2] = cvt2(s[3][0], s[3][1]); w1[3] = cvt2(s[3][2], s[3][3]);
        *(u32x4*)&ldsbase[(size_t)s_r * BK + so0] = w0;
        *(u32x4*)&ldsbase[(size_t)s_r * BK + so1] = w1;
    };

    // frag reads: row&7 == frow&7 (frag base rows are multiples of 8)
    const int frow = lane & 15;
    const int khi  = lane >> 4;
    const int xr   = frow & 7;
    const int oK0  = ((khi)     ^ xr) * 8;
    const int oK1  = ((4 + khi) ^ xr) * 8;

    auto rdA = [&](int buf, int mi, int o) {
        return *(const bf16x8*)&ldsA[buf][wm * 64 + mi * 16 + frow][o];
    };
    auto rdB = [&](int buf, int ni, int o) {
        return *(const bf16x8*)&ldsB[buf][wn * 64 + ni * 16 + frow][o];
    };

    f32x4 acc[4][4];               // 64 VGPR
#pragma unroll
    for (int mi = 0; mi < 4; ++mi)
#pragma unroll
        for (int ni = 0; ni < 4; ++ni)
            acc[mi][ni] = (f32x4){0.f, 0.f, 0.f, 0.f};

    // ---- prologue: stage tile 0 -> buf0; A(1) in flight ----
    ISSUE(srcA, 0, stA); CVTW(&ldsA[0][0][0], stA);
    ISSUE(srcB, 0, stB); CVTW(&ldsB[0][0][0], stB);
    ISSUE(srcA, 1, stA);
    WAITLG(0);
    BAR;

    bf16x8 af[4], bfr[4];

    // 4 phases/tile, one barrier each; counted lgkm waits; writes drained
    // with >= 1 phase of slack except P3's B-writes (as R13/R21).
#pragma unroll 1
    for (int kt = 0; kt < NKT - 1; ++kt) {
        const int rd = kt & 1;
        const bool m2 = (kt + 2 < NKT);
        unsigned short* nA = &ldsA[rd ^ 1][0][0];
        unsigned short* nB = &ldsB[rd ^ 1][0][0];

        // ---- P0: [6r] wait0 | MFMA ni01@ks0 || 2r ; SB0 ; 2w(A) + ISSUE_B
#pragma unroll
        for (int mi = 0; mi < 4; ++mi) af[mi] = rdA(rd, mi, oK0);
        bfr[0] = rdB(rd, 0, oK0); bfr[1] = rdB(rd, 1, oK0);
        WAITLG(0);
        __builtin_amdgcn_s_setprio(1);
#pragma unroll
        for (int mi = 0; mi < 4; ++mi) {
            acc[mi][0] = MFMA16(af[mi], bfr[0], acc[mi][0]);
            acc[mi][1] = MFMA16(af[mi], bfr[1], acc[mi][1]);
        }
        __builtin_amdgcn_s_setprio(0);
        bfr[2] = rdB(rd, 2, oK0); bfr[3] = rdB(rd, 3, oK0);   // 2 reads
        SB0;
        CVTW(nA, stA);                                         // 2 writes (A(kt+1), flight ~1 tile)
        ISSUE(srcB, kt + 1, stB);
        BAR;

        // ---- P1: queue [2r,2w] wait2 | MFMA ni23@ks0 || 6r ; no writes
        WAITLG(2);
        __builtin_amdgcn_s_setprio(1);
#pragma unroll
        for (int mi = 0; mi < 4; ++mi) {
            acc[mi][2] = MFMA16(af[mi], bfr[2], acc[mi][2]);
            acc[mi][3] = MFMA16(af[mi], bfr[3], acc[mi][3]);
        }
        __builtin_amdgcn_s_setprio(0);
#pragma unroll
        for (int mi = 0; mi < 4; ++mi) af[mi] = rdA(rd, mi, oK1);
        bfr[0] = rdB(rd, 0, oK1); bfr[1] = rdB(rd, 1, oK1);
        BAR;

        // ---- P2: queue [2w,6r] wait0 (w old) | MFMA ni01@ks1 || 2r ; 2w(B) + ISSUE_A
        WAITLG(0);
        __builtin_amdgcn_s_setprio(1);
#pragma unroll
        for (int mi = 0; mi < 4; ++mi) {
            acc[mi][0] = MFMA16(af[mi], bfr[0], acc[mi][0]);
            acc[mi][1] = MFMA16(af[mi], bfr[1], acc[mi][1]);
        }
        __builtin_amdgcn_s_setprio(0);
        bfr[2] = rdB(rd, 2, oK1); bfr[3] = rdB(rd, 3, oK1);   // 2 reads
        SB0;
        CVTW(nB, stB);                                         // 2 writes (B(kt+1), flight ~2 phases)
        if (m2) ISSUE(srcA, kt + 2, stA);
        BAR;

        // ---- P3: queue [2r,2w] wait2 | MFMA ni23@ks1 ; seal ----
        WAITLG(2);
        __builtin_amdgcn_s_setprio(1);
#pragma unroll
        for (int mi = 0; mi < 4; ++mi) {
            acc[mi][2] = MFMA16(af[mi], bfr[2], acc[mi][2]);
            acc[mi][3] = MFMA16(af[mi], bfr[3], acc[mi][3]);
        }
        __builtin_amdgcn_s_setprio(0);
        WAITLG(0);                       // drain B-writes
        BAR;                             // buf^1 sealed
    }

    // ---- peeled last tile (no staging) ----
    {
        const int rd = (NKT - 1) & 1;
#pragma unroll
        for (int mi = 0; mi < 4; ++mi) af[mi] = rdA(rd, mi, oK0);
#pragma unroll
        for (int ni = 0; ni < 4; ++ni) bfr[ni] = rdB(rd, ni, oK0);
        WAITLG(0);
#pragma unroll
        for (int mi = 0; mi < 4; ++mi)
#pragma unroll
            for (int ni = 0; ni < 4; ++ni)
                acc[mi][ni] = MFMA16(af[mi], bfr[ni], acc[mi][ni]);
#pragma unroll
        for (int mi = 0; mi < 4; ++mi) af[mi] = rdA(rd, mi, oK1);
#pragma unroll
        for (int ni = 0; ni < 4; ++ni) bfr[ni] = rdB(rd, ni, oK1);
        WAITLG(0);
#pragma unroll
        for (int mi = 0; mi < 4; ++mi)
#pragma unroll
            for (int ni = 0; ni < 4; ++ni)
                acc[mi][ni] = MFMA16(af[mi], bfr[ni], acc[mi][ni]);
    }

    // epilogue: acc layout col=lane&15, row=(lane>>4)*4+r (m89-verified)
#pragma unroll
    for (int ni = 0; ni < 4; ++ni) {
        const int gc = tn * BN + wn * 64 + ni * 16 + frow;
        const float bv = Bias[bidx * NDIM + gc];
#pragma unroll
        for (int mi = 0; mi < 4; ++mi) {
            const int gr0 = tm * BM + wm * 64 + mi * 16 + khi * 4;
            float* po = Out + ((size_t)bidx * MDIM + gr0) * NDIM + gc;
#pragma unroll
            for (int r = 0; r < 4; ++r)
                po[(size_t)r * NDIM] = acc[mi][ni][r] + bv;
        }
    }
}

extern "C" void kernel_launch(void* const* d_in, const int* in_sizes, int n_in,
                              void* d_out, int out_size, void* d_ws, size_t ws_size,
                              hipStream_t stream) {
    const float* X  = (const float*)d_in[0];
    const float* W  = (const float*)d_in[1];
    const float* Bs = (const float*)d_in[2];
    float* Out = (float*)d_out;

    grouped_fc_kernel<<<dim3(512), dim3(1024), 0, stream>>>(X, W, Bs, Out);
}